// Round 1
// baseline (601.114 us; speedup 1.0000x reference)
//
#include <hip/hip_runtime.h>
#include <cstdint>
#include <cstddef>

typedef float floatx4 __attribute__((ext_vector_type(4)));
typedef short bf16x8 __attribute__((ext_vector_type(8)));

#define MFMA(a, b, c) __builtin_amdgcn_mfma_f32_16x16x32_bf16((a), (b), (c), 0, 0, 0)
#define BARRIER() __builtin_amdgcn_s_barrier()
#define LGKM0() asm volatile("s_waitcnt lgkmcnt(0)" ::: "memory")

__device__ __forceinline__ unsigned short f2bf(float f) {
  union { float f; unsigned int u; } v; v.f = f;
  unsigned int u = v.u;
  unsigned int r = (u + 0x7FFFu + ((u >> 16) & 1u)) >> 16;
  return (unsigned short)r;
}

__device__ __forceinline__ void gload_lds16(const unsigned short* g, unsigned short* s) {
  __builtin_amdgcn_global_load_lds(
      (const __attribute__((address_space(1))) unsigned int*)g,
      (__attribute__((address_space(3))) unsigned int*)s, 16, 0, 0);
}

// ------------------------------------------------------------------
// All 6 weight transposes fused into one launch (src [R,C] fp32 ->
// dst [C,R] bf16 with row stride ldd).  Flat grid of 32x32 tiles.
// ------------------------------------------------------------------
__global__ __launch_bounds__(256) void transpose_all(
    const float* __restrict__ w_mlp_in, const float* __restrict__ wq,
    const float* __restrict__ wk, const float* __restrict__ wv,
    const float* __restrict__ w_mlp_out, const float* __restrict__ w_attn_out,
    unsigned short* __restrict__ wcatT, unsigned short* __restrict__ wcat2T) {
  int id = blockIdx.x;
  const float* src; unsigned short* dst; int C, ldd, bx, by, q;
  if (id < 4096)       { src = w_mlp_in;   dst = wcatT;                        C = 4096; ldd = 1024; q = id;         bx = q & 127; by = q >> 7; }
  else if (id < 5120)  { src = wq;         dst = wcatT + (size_t)4096 * 1024;  C = 1024; ldd = 1024; q = id - 4096;  bx = q & 31;  by = q >> 5; }
  else if (id < 6144)  { src = wk;         dst = wcatT + (size_t)5120 * 1024;  C = 1024; ldd = 1024; q = id - 5120;  bx = q & 31;  by = q >> 5; }
  else if (id < 7168)  { src = wv;         dst = wcatT + (size_t)6144 * 1024;  C = 1024; ldd = 1024; q = id - 6144;  bx = q & 31;  by = q >> 5; }
  else if (id < 11264) { src = w_mlp_out;  dst = wcat2T;                       C = 1024; ldd = 5120; q = id - 7168;  bx = q & 31;  by = q >> 5; }
  else                 { src = w_attn_out; dst = wcat2T + 4096;                C = 1024; ldd = 5120; q = id - 11264; bx = q & 31;  by = q >> 5; }
  __shared__ float tile[32][33];
  int tx = threadIdx.x & 31, ty = threadIdx.x >> 5;
#pragma unroll
  for (int i = 0; i < 4; i++) {
    int r = ty + i * 8;
    tile[r][tx] = src[(size_t)(by * 32 + r) * C + bx * 32 + tx];
  }
  __syncthreads();
#pragma unroll
  for (int i = 0; i < 4; i++) {
    int r = ty + i * 8;
    dst[(size_t)(bx * 32 + r) * ldd + by * 32 + tx] = f2bf(tile[tx][r]);
  }
}

// ------------------------------------------------------------------
// RMSNorm: x [8192,1024] fp32 -> xn bf16.  One block per row.
// ------------------------------------------------------------------
__global__ __launch_bounds__(256) void rmsnorm_kernel(
    const float* __restrict__ x, const float* __restrict__ scale,
    unsigned short* __restrict__ xn) {
  int row = blockIdx.x;
  const float4 v = ((const float4*)(x + (size_t)row * 1024))[threadIdx.x];
  float ss = v.x * v.x + v.y * v.y + v.z * v.z + v.w * v.w;
#pragma unroll
  for (int off = 1; off < 64; off <<= 1) ss += __shfl_xor(ss, off, 64);
  __shared__ float ws4[4];
  if ((threadIdx.x & 63) == 0) ws4[threadIdx.x >> 6] = ss;
  __syncthreads();
  float tot = ws4[0] + ws4[1] + ws4[2] + ws4[3];
  float rs = rsqrtf(tot * (1.0f / 1024.0f) + 1e-6f);
  const float4 sc = ((const float4*)scale)[threadIdx.x];
  uint2 o;
  o.x = (unsigned)f2bf(v.x * rs * sc.x) | ((unsigned)f2bf(v.y * rs * sc.y) << 16);
  o.y = (unsigned)f2bf(v.z * rs * sc.z) | ((unsigned)f2bf(v.w * rs * sc.w) << 16);
  ((uint2*)(xn + (size_t)row * 1024))[threadIdx.x] = o;
}

// ------------------------------------------------------------------
// 256x256-tile pipelined GEMM: C[M,N] = A[M,K] * BT[N,K]^T (bf16).
// BK=64, 512 threads = 8 waves (2M x 4N), wave tile 128x64,
// acc[8][4] (128 VGPR).  LDS 128 KiB: double-buffered A,B tiles as
// 16-row x 32-k chunks (1 KiB each, 1 chunk = 1 wave gload_lds line).
//
// HYBRID SWIZZLE (carried over, measured 0 bank-conflict cycles):
// staging lane L -> (row L>>2, granule (L&3)^((L>>3)&3)); frag read
// fo = (4*l15 + (quad ^ ((l15>>1)&3)))*8.
//
// 4-phase/K-tile schedule (T3+T4+T5, counted vmcnt never 0 in loop):
//  ph0: ds_read b[0-1],a_lo | stage t+1:B0 | bar,lgkm0 | prio 16xMFMA | bar
//  ph1: ds_read b[2-3]      | stage t+1:B1 | bar,lgkm0 | prio 16xMFMA | bar
//  ph2: ds_read a_hi        |              | bar,lgkm0 | prio 16xMFMA | bar
//  ph3: stage t+2:A0,A1 (into buf cur!)    | bar       | prio 16xMFMA |
//       vmcnt(4) | bar
// Safety: lgkm0 before each MFMA + closing barrier => all waves'
// ds_reads of a region complete before the next phase issues the
// overwriting stage; boundary vmcnt(4) leaves t+2:A0,A1 (4 loads) in
// flight while guaranteeing all of tile t+1 has landed (in-order
// vmem completion).  NT must be >= 2 (here 16 and 80).
//
// MODE 6 (fused input): col<4096 gelu->cat[row*5120+col];
//   else q*0.125 / k scatter [B,H,S,HD], v -> [B,H,HD,S]
// MODE 7 (fused output): out[row*1024+col]=v+b1[col]+b2[col]+resid
// ------------------------------------------------------------------
template <int MODE>
__global__ __launch_bounds__(512, 2) void gemm256_bt(
    const unsigned short* __restrict__ A, const unsigned short* __restrict__ BT,
    int K, void* __restrict__ outp,
    const float* __restrict__ bias1, const float* __restrict__ bias2,
    const float* __restrict__ resid,
    int msplit, int tm, int tn,
    unsigned short* __restrict__ q_out, unsigned short* __restrict__ k_out,
    unsigned short* __restrict__ v_out) {
  __shared__ unsigned short As[2][2][16][512];  // [buf][kk][rowchunk][chunk]
  __shared__ unsigned short Bs[2][2][16][512];

  int id = blockIdx.x + gridDim.x * blockIdx.y;
  int xcd = id & 7, j = id >> 3;
  int mh = xcd % msplit, nq = xcd / msplit;
  int by = mh * tm + j / tn;
  int bx = nq * tn + j % tn;
  int m0 = by * 256, n0 = bx * 256;

  int tid = threadIdx.x, lane = tid & 63, wave = tid >> 6;
  int l15 = lane & 15, quad = lane >> 4;
  int wm = wave >> 2, wn = wave & 3;   // 2 x 4 wave grid

  // staging geometry: lane L -> (row L>>2, 16B-granule (L&3)^((L>>3)&3))
  int lr = lane >> 2;
  int lg = (lane & 3) ^ ((lane >> 3) & 3);
  const unsigned short* gA = A + (size_t)(m0 + wave * 16 + lr) * K + lg * 8;
  const unsigned short* gB = BT + (size_t)(n0 + wave * 16 + lr) * K + lg * 8;
  const size_t rowoff = (size_t)128 * K;  // half-tile row offset
  int NT = K >> 6;

#define STAGE_A(buf, half, kelem) do {                                        \
    const unsigned short* _s = gA + (size_t)(half) * rowoff + (kelem);        \
    gload_lds16(_s,      &As[buf][0][(half) * 8 + wave][lane * 8]);           \
    gload_lds16(_s + 32, &As[buf][1][(half) * 8 + wave][lane * 8]);           \
  } while (0)
#define STAGE_B(buf, half, kelem) do {                                        \
    const unsigned short* _s = gB + (size_t)(half) * rowoff + (kelem);        \
    gload_lds16(_s,      &Bs[buf][0][(half) * 8 + wave][lane * 8]);           \
    gload_lds16(_s + 32, &Bs[buf][1][(half) * 8 + wave][lane * 8]);           \
  } while (0)

  // frag read offset: conflict-free inverse of the staging map
  int fo = (4 * l15 + (quad ^ ((l15 >> 1) & 3))) * 8;

  floatx4 acc[8][4] = {};

  // prologue: tile0 full + tile1 A-halves; drain tile0 (vmcnt(4) leaves
  // the 4 tile1:A loads in flight = steady state)
  STAGE_A(0, 0, 0); STAGE_A(0, 1, 0);
  STAGE_B(0, 0, 0); STAGE_B(0, 1, 0);
  STAGE_A(1, 0, 64); STAGE_A(1, 1, 64);
  asm volatile("s_waitcnt vmcnt(4)" ::: "memory");
  BARRIER();

  for (int t = 0; t < NT; ++t) {
    int cur = t & 1;
    bf16x8 a0[4][2], a1[4][2], b[4][2];

    // ---------------- phase 0: b[0-1] + a_lo; stage t+1:B0
#pragma unroll
    for (int n = 0; n < 2; n++) {
      b[n][0] = *(const bf16x8*)&Bs[cur][0][wn * 4 + n][fo];
      b[n][1] = *(const bf16x8*)&Bs[cur][1][wn * 4 + n][fo];
    }
#pragma unroll
    for (int m = 0; m < 4; m++) {
      a0[m][0] = *(const bf16x8*)&As[cur][0][wm * 8 + m][fo];
      a0[m][1] = *(const bf16x8*)&As[cur][1][wm * 8 + m][fo];
    }
    if (t + 1 < NT) STAGE_B(cur ^ 1, 0, (t + 1) << 6);
    BARRIER(); LGKM0();
    __builtin_amdgcn_s_setprio(1);
#pragma unroll
    for (int m = 0; m < 4; m++)
#pragma unroll
      for (int n = 0; n < 2; n++) {
        acc[m][n] = MFMA(a0[m][0], b[n][0], acc[m][n]);
        acc[m][n] = MFMA(a0[m][1], b[n][1], acc[m][n]);
      }
    __builtin_amdgcn_s_setprio(0);
    BARRIER();

    // ---------------- phase 1: b[2-3]; stage t+1:B1
#pragma unroll
    for (int n = 2; n < 4; n++) {
      b[n][0] = *(const bf16x8*)&Bs[cur][0][wn * 4 + n][fo];
      b[n][1] = *(const bf16x8*)&Bs[cur][1][wn * 4 + n][fo];
    }
    if (t + 1 < NT) STAGE_B(cur ^ 1, 1, (t + 1) << 6);
    BARRIER(); LGKM0();
    __builtin_amdgcn_s_setprio(1);
#pragma unroll
    for (int m = 0; m < 4; m++)
#pragma unroll
      for (int n = 2; n < 4; n++) {
        acc[m][n] = MFMA(a0[m][0], b[n][0], acc[m][n]);
        acc[m][n] = MFMA(a0[m][1], b[n][1], acc[m][n]);
      }
    __builtin_amdgcn_s_setprio(0);
    BARRIER();

    // ---------------- phase 2: a_hi
#pragma unroll
    for (int m = 0; m < 4; m++) {
      a1[m][0] = *(const bf16x8*)&As[cur][0][wm * 8 + 4 + m][fo];
      a1[m][1] = *(const bf16x8*)&As[cur][1][wm * 8 + 4 + m][fo];
    }
    BARRIER(); LGKM0();
    __builtin_amdgcn_s_setprio(1);
#pragma unroll
    for (int m = 0; m < 4; m++)
#pragma unroll
      for (int n = 0; n < 2; n++) {
        acc[m + 4][n] = MFMA(a1[m][0], b[n][0], acc[m + 4][n]);
        acc[m + 4][n] = MFMA(a1[m][1], b[n][1], acc[m + 4][n]);
      }
    __builtin_amdgcn_s_setprio(0);
    BARRIER();

    // ---------------- phase 3: stage t+2:A (into buf cur); boundary wait
    if (t + 2 < NT) { STAGE_A(cur, 0, (t + 2) << 6); STAGE_A(cur, 1, (t + 2) << 6); }
    BARRIER();
    __builtin_amdgcn_s_setprio(1);
#pragma unroll
    for (int m = 0; m < 4; m++)
#pragma unroll
      for (int n = 2; n < 4; n++) {
        acc[m + 4][n] = MFMA(a1[m][0], b[n][0], acc[m + 4][n]);
        acc[m + 4][n] = MFMA(a1[m][1], b[n][1], acc[m + 4][n]);
      }
    __builtin_amdgcn_s_setprio(0);
    if (t + 2 < NT) { asm volatile("s_waitcnt vmcnt(4)" ::: "memory"); }
    else            { asm volatile("s_waitcnt vmcnt(0)" ::: "memory"); }
    BARRIER();
  }
#undef STAGE_A
#undef STAGE_B

#pragma unroll
  for (int im = 0; im < 8; im++) {
#pragma unroll
    for (int in_ = 0; in_ < 4; in_++) {
#pragma unroll
      for (int r = 0; r < 4; r++) {
        int row = m0 + wm * 128 + im * 16 + quad * 4 + r;
        int col = n0 + wn * 64 + in_ * 16 + l15;
        float v = acc[im][in_][r];
        if constexpr (MODE == 6) {
          if (n0 < 4096) {
            float z = 0.7978845608028654f * (v + 0.044715f * v * v * v);
            float e = __expf(2.0f * z);
            float th = 1.0f - 2.0f / (e + 1.0f);
            ((unsigned short*)outp)[(size_t)row * 5120 + col] = f2bf(0.5f * v * (1.0f + th));
          } else {
            int seg = (n0 - 4096) >> 10;          // 0=q 1=k 2=v (tile-uniform)
            int cs = col - 4096 - (seg << 10);
            int b_ = row >> 11, s = row & 2047, h = cs >> 6, hd = cs & 63;
            if (seg == 0)
              q_out[(((size_t)(b_ * 16 + h)) * 2048 + s) * 64 + hd] = f2bf(v * 0.125f);
            else if (seg == 1)
              k_out[(((size_t)(b_ * 16 + h)) * 2048 + s) * 64 + hd] = f2bf(v);
            else
              v_out[(((size_t)(b_ * 16 + h)) * 64 + hd) * 2048 + s] = f2bf(v);
          }
        } else {
          size_t idx = (size_t)row * 1024 + col;
          ((float*)outp)[idx] = v + bias1[col] + bias2[col] + resid[idx];
        }
      }
    }
  }
}

// ------------------------------------------------------------------
// Flash attention, no-max additive variant (unchanged this round).
// q pre-scaled by 0.125.  q,k [B,H,S,HD]; v [B,H,HD,S] bf16.
// av -> cat cols 4096..5120.  4 waves x 32 q rows; kv tile 64.
// ------------------------------------------------------------------
__global__ __launch_bounds__(256, 2) void flash_attn(
    const unsigned short* __restrict__ q_buf, const unsigned short* __restrict__ k_buf,
    const unsigned short* __restrict__ v_buf, unsigned short* __restrict__ cat) {
  constexpr int S = 2048, HD = 64;
  constexpr int LK = 72, LV = 72, LP = 68;
  __shared__ unsigned short Ks[64 * LK];
  __shared__ unsigned short Vs[64 * LV];
  __shared__ unsigned short Ps[4][32 * LP];

  int id = blockIdx.x + gridDim.x * blockIdx.y;   // grid (16, 64)
  int xcd = id & 7, j = id >> 3;                  // j in [0,128)
  int bh = xcd * 8 + (j >> 4);
  int qbk = j & 15;

  int t = threadIdx.x, lane = t & 63, wave = t >> 6;
  int l15 = lane & 15, quad = lane >> 4;

  const unsigned short* qp = q_buf + (size_t)bh * S * HD;
  const unsigned short* kp = k_buf + (size_t)bh * S * HD;
  const unsigned short* vp = v_buf + (size_t)bh * HD * S;

  int q0 = qbk * 128 + wave * 32;
  bf16x8 aQ[2][2];
#pragma unroll
  for (int qf = 0; qf < 2; qf++) {
    aQ[qf][0] = *(const bf16x8*)&qp[(size_t)(q0 + qf * 16 + l15) * HD + quad * 8];
    aQ[qf][1] = *(const bf16x8*)&qp[(size_t)(q0 + qf * 16 + l15) * HD + 32 + quad * 8];
  }

  floatx4 acc_o[2][4] = {};
  float lrow[2][4] = {};

  int kr = t >> 3, kc = (t & 7) * 8;

  uint4 rK0 = *(const uint4*)&kp[(size_t)kr * HD + kc];
  uint4 rK1 = *(const uint4*)&kp[(size_t)(kr + 32) * HD + kc];
  uint4 rV0 = *(const uint4*)&vp[(size_t)kr * S + kc];
  uint4 rV1 = *(const uint4*)&vp[(size_t)(kr + 32) * S + kc];

  for (int kv = 0; kv < S; kv += 64) {
    __syncthreads();
    *(uint4*)&Ks[kr * LK + kc] = rK0;
    *(uint4*)&Ks[(kr + 32) * LK + kc] = rK1;
    *(uint4*)&Vs[kr * LV + kc] = rV0;
    *(uint4*)&Vs[(kr + 32) * LV + kc] = rV1;
    __syncthreads();
    if (kv + 64 < S) {
      rK0 = *(const uint4*)&kp[(size_t)(kv + 64 + kr) * HD + kc];
      rK1 = *(const uint4*)&kp[(size_t)(kv + 64 + kr + 32) * HD + kc];
      rV0 = *(const uint4*)&vp[(size_t)kr * S + kv + 64 + kc];
      rV1 = *(const uint4*)&vp[(size_t)(kr + 32) * S + kv + 64 + kc];
    }

    floatx4 z[2][4];
#pragma unroll
    for (int cg = 0; cg < 4; cg++) {
      bf16x8 bk0 = *(const bf16x8*)&Ks[(cg * 16 + l15) * LK + quad * 8];
      bf16x8 bk1 = *(const bf16x8*)&Ks[(cg * 16 + l15) * LK + 32 + quad * 8];
#pragma unroll
      for (int qf = 0; qf < 2; qf++) {
        floatx4 acc = {};
        acc = MFMA(aQ[qf][0], bk0, acc);
        acc = MFMA(aQ[qf][1], bk1, acc);
        z[qf][cg] = acc;
      }
    }
#pragma unroll
    for (int qf = 0; qf < 2; qf++)
#pragma unroll
      for (int cg = 0; cg < 4; cg++)
#pragma unroll
        for (int r = 0; r < 4; r++) {
          float e = __expf(z[qf][cg][r]);
          lrow[qf][r] += e;
          Ps[wave][(qf * 16 + quad * 4 + r) * LP + cg * 16 + l15] = f2bf(e);
        }
    asm volatile("s_waitcnt lgkmcnt(0)" ::: "memory");
#pragma unroll
    for (int c = 0; c < 2; c++) {
      bf16x8 aP[2];
#pragma unroll
      for (int qf = 0; qf < 2; qf++) {
        const unsigned short* pp = &Ps[wave][(qf * 16 + l15) * LP + c * 32 + quad * 8];
        ((uint2*)&aP[qf])[0] = *(const uint2*)pp;
        ((uint2*)&aP[qf])[1] = *(const uint2*)(pp + 4);
      }
#pragma unroll
      for (int n = 0; n < 4; n++) {
        bf16x8 bv = *(const bf16x8*)&Vs[(n * 16 + l15) * LV + c * 32 + quad * 8];
        acc_o[0][n] = MFMA(aP[0], bv, acc_o[0][n]);
        acc_o[1][n] = MFMA(aP[1], bv, acc_o[1][n]);
      }
    }
  }

#pragma unroll
  for (int qf = 0; qf < 2; qf++)
#pragma unroll
    for (int r = 0; r < 4; r++) {
      float s = lrow[qf][r];
#pragma unroll
      for (int off = 1; off < 16; off <<= 1) s += __shfl_xor(s, off, 16);
      lrow[qf][r] = s;
    }

  int b_ = bh >> 4, h = bh & 15;
#pragma unroll
  for (int qf = 0; qf < 2; qf++)
#pragma unroll
    for (int r = 0; r < 4; r++) {
      float inv = 1.0f / lrow[qf][r];
      int srow = q0 + qf * 16 + quad * 4 + r;
      size_t base = ((size_t)(b_ * 2048 + srow)) * 5120 + 4096 + h * 64;
#pragma unroll
      for (int n = 0; n < 4; n++)
        cat[base + n * 16 + l15] = f2bf(acc_o[qf][n][r] * inv);
    }
}

// ------------------------------------------------------------------
extern "C" void kernel_launch(void* const* d_in, const int* in_sizes, int n_in,
                              void* d_out, int out_size, void* d_ws, size_t ws_size,
                              hipStream_t stream) {
  (void)in_sizes; (void)n_in; (void)out_size; (void)ws_size;
  const float* x          = (const float*)d_in[0];
  const float* pns        = (const float*)d_in[1];
  const float* w_mlp_in   = (const float*)d_in[2];
  const float* wq         = (const float*)d_in[3];
  const float* wk         = (const float*)d_in[4];
  const float* wv         = (const float*)d_in[5];
  const float* w_mlp_out  = (const float*)d_in[6];
  const float* b_mlp_out  = (const float*)d_in[7];
  const float* w_attn_out = (const float*)d_in[8];
  const float* b_attn_out = (const float*)d_in[9];
  float* out = (float*)d_out;

  char* ws = (char*)d_ws;
  size_t off = 0;
  auto alloc = [&](size_t bytes) {
    void* p = ws + off;
    off += (bytes + 255) & ~(size_t)255;
    return p;
  };
  const size_t M = 8192;
  unsigned short* xn     = (unsigned short*)alloc(M * 1024 * 2);
  unsigned short* wcatT  = (unsigned short*)alloc((size_t)7168 * 1024 * 2);  // [mlp_in|q|k|v][N,K]
  unsigned short* wcat2T = (unsigned short*)alloc((size_t)1024 * 5120 * 2);  // [N=1024, K=5120]
  unsigned short* cat    = (unsigned short*)alloc(M * 5120 * 2);             // [h | av]
  unsigned short* qb     = (unsigned short*)alloc(M * 1024 * 2);
  unsigned short* kb     = (unsigned short*)alloc(M * 1024 * 2);
  unsigned short* vb     = (unsigned short*)alloc(M * 1024 * 2);

  transpose_all<<<dim3(12288), 256, 0, stream>>>(
      w_mlp_in, wq, wk, wv, w_mlp_out, w_attn_out, wcatT, wcat2T);

  rmsnorm_kernel<<<dim3(8192), 256, 0, stream>>>(x, pns, xn);

  // fused input GEMM: [8192,1024] x [7168,1024]^T; 256x256 tiles,
  // grid 32x28 = 896 blocks (896%8==0); msplit=2 nsplit=4 (tm=16,tn=7)
  gemm256_bt<6><<<dim3(896), 512, 0, stream>>>(
      xn, wcatT, 1024, cat, nullptr, nullptr, nullptr, 2, 16, 7, qb, kb, vb);

  flash_attn<<<dim3(16, 64), 256, 0, stream>>>(qb, kb, vb, cat);

  // fused output GEMM: [8192,5120] x [1024,5120]^T; 256x256 tiles,
  // grid 32x4 = 128 blocks; msplit=2 nsplit=4 (tm=16,tn=1)
  gemm256_bt<7><<<dim3(128), 512, 0, stream>>>(
      cat, wcat2T, 5120, out, b_mlp_out, b_attn_out, x, 2, 16, 1, nullptr, nullptr, nullptr);
}

// Round 2
// 562.058 us; speedup vs baseline: 1.0695x; 1.0695x over previous
//
#include <hip/hip_runtime.h>
#include <cstdint>
#include <cstddef>

typedef float floatx4 __attribute__((ext_vector_type(4)));
typedef short bf16x8 __attribute__((ext_vector_type(8)));

#define MFMA(a, b, c) __builtin_amdgcn_mfma_f32_16x16x32_bf16((a), (b), (c), 0, 0, 0)
#define BARRIER() __builtin_amdgcn_s_barrier()

__device__ __forceinline__ unsigned short f2bf(float f) {
  union { float f; unsigned int u; } v; v.f = f;
  unsigned int u = v.u;
  unsigned int r = (u + 0x7FFFu + ((u >> 16) & 1u)) >> 16;
  return (unsigned short)r;
}

__device__ __forceinline__ void gload_lds16(const unsigned short* g, unsigned short* s) {
  __builtin_amdgcn_global_load_lds(
      (const __attribute__((address_space(1))) unsigned int*)g,
      (__attribute__((address_space(3))) unsigned int*)s, 16, 0, 0);
}

// ------------------------------------------------------------------
// All 6 weight transposes fused into one launch (src [R,C] fp32 ->
// dst [C,R] bf16 with row stride ldd).  Flat grid of 32x32 tiles.
// ------------------------------------------------------------------
__global__ __launch_bounds__(256) void transpose_all(
    const float* __restrict__ w_mlp_in, const float* __restrict__ wq,
    const float* __restrict__ wk, const float* __restrict__ wv,
    const float* __restrict__ w_mlp_out, const float* __restrict__ w_attn_out,
    unsigned short* __restrict__ wcatT, unsigned short* __restrict__ wcat2T) {
  int id = blockIdx.x;
  const float* src; unsigned short* dst; int C, ldd, bx, by, q;
  if (id < 4096)       { src = w_mlp_in;   dst = wcatT;                        C = 4096; ldd = 1024; q = id;         bx = q & 127; by = q >> 7; }
  else if (id < 5120)  { src = wq;         dst = wcatT + (size_t)4096 * 1024;  C = 1024; ldd = 1024; q = id - 4096;  bx = q & 31;  by = q >> 5; }
  else if (id < 6144)  { src = wk;         dst = wcatT + (size_t)5120 * 1024;  C = 1024; ldd = 1024; q = id - 5120;  bx = q & 31;  by = q >> 5; }
  else if (id < 7168)  { src = wv;         dst = wcatT + (size_t)6144 * 1024;  C = 1024; ldd = 1024; q = id - 6144;  bx = q & 31;  by = q >> 5; }
  else if (id < 11264) { src = w_mlp_out;  dst = wcat2T;                       C = 1024; ldd = 5120; q = id - 7168;  bx = q & 31;  by = q >> 5; }
  else                 { src = w_attn_out; dst = wcat2T + 4096;                C = 1024; ldd = 5120; q = id - 11264; bx = q & 31;  by = q >> 5; }
  __shared__ float tile[32][33];
  int tx = threadIdx.x & 31, ty = threadIdx.x >> 5;
#pragma unroll
  for (int i = 0; i < 4; i++) {
    int r = ty + i * 8;
    tile[r][tx] = src[(size_t)(by * 32 + r) * C + bx * 32 + tx];
  }
  __syncthreads();
#pragma unroll
  for (int i = 0; i < 4; i++) {
    int r = ty + i * 8;
    dst[(size_t)(bx * 32 + r) * ldd + by * 32 + tx] = f2bf(tile[tx][r]);
  }
}

// ------------------------------------------------------------------
// RMSNorm: x [8192,1024] fp32 -> xn bf16.  One block per row.
// ------------------------------------------------------------------
__global__ __launch_bounds__(256) void rmsnorm_kernel(
    const float* __restrict__ x, const float* __restrict__ scale,
    unsigned short* __restrict__ xn) {
  int row = blockIdx.x;
  const float4 v = ((const float4*)(x + (size_t)row * 1024))[threadIdx.x];
  float ss = v.x * v.x + v.y * v.y + v.z * v.z + v.w * v.w;
#pragma unroll
  for (int off = 1; off < 64; off <<= 1) ss += __shfl_xor(ss, off, 64);
  __shared__ float ws4[4];
  if ((threadIdx.x & 63) == 0) ws4[threadIdx.x >> 6] = ss;
  __syncthreads();
  float tot = ws4[0] + ws4[1] + ws4[2] + ws4[3];
  float rs = rsqrtf(tot * (1.0f / 1024.0f) + 1e-6f);
  const float4 sc = ((const float4*)scale)[threadIdx.x];
  uint2 o;
  o.x = (unsigned)f2bf(v.x * rs * sc.x) | ((unsigned)f2bf(v.y * rs * sc.y) << 16);
  o.y = (unsigned)f2bf(v.z * rs * sc.z) | ((unsigned)f2bf(v.w * rs * sc.w) << 16);
  ((uint2*)(xn + (size_t)row * 1024))[threadIdx.x] = o;
}

// ------------------------------------------------------------------
// Pipelined GEMM: C[M,N] = A[M,K] * BT[N,K]^T (bf16), BN=256,
// BM = MR*32 (MR=8 -> 256x256, MR=4 -> 128x256).  512 thr = 8 waves
// (2M x 4N); wave tile (MR*16) x 64; acc[MR][4].
//
// K-tile (BK=64) split into 4 MFMA clusters (kk in {0,1} x m-half),
// SOFTWARE-PIPELINED: cluster c issues cluster c+1's ds_reads BEFORE
// its own MFMAs, so the compiler's counted lgkmcnt lets MFMA cover
// the next reads' latency (R1's barrier+lgkmcnt(0) per phase was
// fully serial: MfmaUtil 22%).  Only 2 barriers / K-tile, each with
// a counted vmcnt validating exactly the half-K regions about to be
// read (never vmcnt(0) in steady state):
//  c0: stage A-kk0(t+1)          | read aH0          | 16 MFMA (lo,kk0)
//  c1: stage B-kk0(t+1) | vmcnt(NSA+2) BAR | read aL1,bk1 | MFMA (hi,kk0)
//  c2: stage A-kk1(t+1)          | read aH1          | MFMA (lo,kk1)
//  c3: stage B-kk1(t+1) | vmcnt(NSA+2) BAR | read aL0',bk0' (buf^1)
//                                                    | MFMA (hi,kk1)
// vmcnt bookkeeping (per wave, in-order): at c1 outstanding =
// [A1(t),B1(t),A0(t+1),B0(t+1)] -> leave last NSA+2 => A1(t),B1(t)
// landed (needed by c1's reads).  At c3: [A0..B1 of t+1] -> leave
// NSA+2 => A0,B0(t+1) landed (needed by c0' reads).  Barrier makes
// it cross-wave.  WAR: every region overwrite is >=1 barrier after
// the lgkm-wait of its last consumer MFMA (verified per region).
// Last tile: vmcnt(0) at c1, skip c3 prefetch.
//
// HYBRID SWIZZLE (measured 0 conflict cycles): staging lane L ->
// (row L>>2, granule (L&3)^((L>>3)&3)); frag read
// fo=(4*l15+(quad^((l15>>1)&3)))*8.
//
// MODE 6 (fused input): col<4096 gelu->cat[row*5120+col];
//   else q*0.125 / k scatter [B,H,S,HD], v -> [B,H,HD,S]
// MODE 7 (fused output): out[row*1024+col]=v+b1[col]+b2[col]+resid
// ------------------------------------------------------------------
template <int MODE, int MR>
__global__ __launch_bounds__(512, 2) void gemm256_bt(
    const unsigned short* __restrict__ A, const unsigned short* __restrict__ BT,
    int K, void* __restrict__ outp,
    const float* __restrict__ bias1, const float* __restrict__ bias2,
    const float* __restrict__ resid,
    int msplit, int tm, int tn,
    unsigned short* __restrict__ q_out, unsigned short* __restrict__ k_out,
    unsigned short* __restrict__ v_out) {
  constexpr int RCA = MR * 2;       // A row-chunks (16 rows each)
  constexpr int NSA = MR / 4;       // A stage gloads per wave per region
  __shared__ unsigned short As[2][2][RCA][512];  // [buf][kk][chunk][..]
  __shared__ unsigned short Bs[2][2][16][512];

  int id = blockIdx.x + gridDim.x * blockIdx.y;
  int xcd = id & 7, j = id >> 3;
  int mh = xcd % msplit, nq = xcd / msplit;
  int by = mh * tm + j / tn;
  int bx = nq * tn + j % tn;
  int m0 = by * (MR * 32), n0 = bx * 256;

  int tid = threadIdx.x, lane = tid & 63, wave = tid >> 6;
  int l15 = lane & 15, quad = lane >> 4;
  int wm = wave >> 2, wn = wave & 3;   // 2 x 4 wave grid

  // staging geometry
  int lr = lane >> 2;
  int lg = (lane & 3) ^ ((lane >> 3) & 3);
  const unsigned short* gA = A + (size_t)(m0 + wave * 16 + lr) * K + lg * 8;
  const unsigned short* gB = BT + (size_t)(n0 + wave * 16 + lr) * K + lg * 8;
  int NT = K >> 6;

#define STAGE_A(buf, kk, kel) do {                                        \
    _Pragma("unroll")                                                     \
    for (int s = 0; s < NSA; s++)                                         \
      gload_lds16(gA + (size_t)s * 128 * K + (kel) + (kk) * 32,           \
                  &As[buf][kk][wave + s * 8][lane * 8]);                  \
  } while (0)
#define STAGE_B(buf, kk, kel) do {                                        \
    _Pragma("unroll")                                                     \
    for (int s = 0; s < 2; s++)                                           \
      gload_lds16(gB + (size_t)s * 128 * K + (kel) + (kk) * 32,           \
                  &Bs[buf][kk][wave + s * 8][lane * 8]);                  \
  } while (0)
#define WAITV() do {                                                      \
    if constexpr (NSA == 2) asm volatile("s_waitcnt vmcnt(4)" ::: "memory"); \
    else                    asm volatile("s_waitcnt vmcnt(3)" ::: "memory"); \
  } while (0)
#define RD_A(dst, buf, kk, half) do {                                     \
    _Pragma("unroll")                                                     \
    for (int mf = 0; mf < MR / 2; mf++)                                   \
      dst[mf] = *(const bf16x8*)&As[buf][kk][wm * MR + (half) * (MR / 2) + mf][fo]; \
  } while (0)
#define RD_B(dst, buf, kk) do {                                           \
    _Pragma("unroll")                                                     \
    for (int n = 0; n < 4; n++)                                           \
      dst[n] = *(const bf16x8*)&Bs[buf][kk][wn * 4 + n][fo];              \
  } while (0)
#define CLUSTER(abase, af, bf) do {                                       \
    __builtin_amdgcn_s_setprio(1);                                        \
    _Pragma("unroll")                                                     \
    for (int mf = 0; mf < MR / 2; mf++)                                   \
      _Pragma("unroll")                                                   \
      for (int n = 0; n < 4; n++)                                         \
        acc[(abase) + mf][n] = MFMA(af[mf], bf[n], acc[(abase) + mf][n]); \
    __builtin_amdgcn_s_setprio(0);                                        \
  } while (0)

  // frag read offset: conflict-free inverse of the staging map
  int fo = (4 * l15 + (quad ^ ((l15 >> 1) & 3))) * 8;

  floatx4 acc[MR][4] = {};
  bf16x8 aL0[MR / 2], aH0[MR / 2], aL1[MR / 2], aH1[MR / 2], bk0[4], bk1[4];

  // prologue: full tile0 staged (order A0,B0,A1,B1); validate A0,B0
  STAGE_A(0, 0, 0); STAGE_B(0, 0, 0); STAGE_A(0, 1, 0); STAGE_B(0, 1, 0);
  WAITV();
  BARRIER();
  __builtin_amdgcn_sched_barrier(0);
  RD_A(aL0, 0, 0, 0); RD_B(bk0, 0, 0);

  for (int t = 0; t < NT; ++t) {
    int cur = t & 1, nxt = cur ^ 1, k1 = (t + 1) << 6;
    bool pf = (t + 1 < NT);
    // ---- c0: (m-lo, kk0)
    if (pf) STAGE_A(nxt, 0, k1);
    RD_A(aH0, cur, 0, 1);
    CLUSTER(0, aL0, bk0);
    // ---- c1: (m-hi, kk0)
    if (pf) {
      STAGE_B(nxt, 0, k1);
      WAITV();
    } else {
      asm volatile("s_waitcnt vmcnt(0)" ::: "memory");
    }
    BARRIER();
    __builtin_amdgcn_sched_barrier(0);
    RD_A(aL1, cur, 1, 0); RD_B(bk1, cur, 1);
    CLUSTER(MR / 2, aH0, bk0);
    // ---- c2: (m-lo, kk1)
    if (pf) STAGE_A(nxt, 1, k1);
    RD_A(aH1, cur, 1, 1);
    CLUSTER(0, aL1, bk1);
    // ---- c3: (m-hi, kk1)
    if (pf) {
      STAGE_B(nxt, 1, k1);
      WAITV();
      BARRIER();
      __builtin_amdgcn_sched_barrier(0);
      RD_A(aL0, nxt, 0, 0); RD_B(bk0, nxt, 0);
    }
    CLUSTER(MR / 2, aH1, bk1);
  }
#undef STAGE_A
#undef STAGE_B
#undef WAITV
#undef RD_A
#undef RD_B
#undef CLUSTER

#pragma unroll
  for (int im = 0; im < MR; im++) {
#pragma unroll
    for (int in_ = 0; in_ < 4; in_++) {
#pragma unroll
      for (int r = 0; r < 4; r++) {
        int row = m0 + wm * (MR * 16) + im * 16 + quad * 4 + r;
        int col = n0 + wn * 64 + in_ * 16 + l15;
        float v = acc[im][in_][r];
        if constexpr (MODE == 6) {
          if (n0 < 4096) {
            float z = 0.7978845608028654f * (v + 0.044715f * v * v * v);
            float e = __expf(2.0f * z);
            float th = 1.0f - 2.0f / (e + 1.0f);
            ((unsigned short*)outp)[(size_t)row * 5120 + col] = f2bf(0.5f * v * (1.0f + th));
          } else {
            int seg = (n0 - 4096) >> 10;          // 0=q 1=k 2=v (tile-uniform)
            int cs = col - 4096 - (seg << 10);
            int b_ = row >> 11, s = row & 2047, h = cs >> 6, hd = cs & 63;
            if (seg == 0)
              q_out[(((size_t)(b_ * 16 + h)) * 2048 + s) * 64 + hd] = f2bf(v * 0.125f);
            else if (seg == 1)
              k_out[(((size_t)(b_ * 16 + h)) * 2048 + s) * 64 + hd] = f2bf(v);
            else
              v_out[(((size_t)(b_ * 16 + h)) * 64 + hd) * 2048 + s] = f2bf(v);
          }
        } else {
          size_t idx = (size_t)row * 1024 + col;
          ((float*)outp)[idx] = v + bias1[col] + bias2[col] + resid[idx];
        }
      }
    }
  }
}

// ------------------------------------------------------------------
// Flash attention, no-max additive variant (unchanged this round).
// q pre-scaled by 0.125.  q,k [B,H,S,HD]; v [B,H,HD,S] bf16.
// av -> cat cols 4096..5120.  4 waves x 32 q rows; kv tile 64.
// ------------------------------------------------------------------
__global__ __launch_bounds__(256, 2) void flash_attn(
    const unsigned short* __restrict__ q_buf, const unsigned short* __restrict__ k_buf,
    const unsigned short* __restrict__ v_buf, unsigned short* __restrict__ cat) {
  constexpr int S = 2048, HD = 64;
  constexpr int LK = 72, LV = 72, LP = 68;
  __shared__ unsigned short Ks[64 * LK];
  __shared__ unsigned short Vs[64 * LV];
  __shared__ unsigned short Ps[4][32 * LP];

  int id = blockIdx.x + gridDim.x * blockIdx.y;   // grid (16, 64)
  int xcd = id & 7, j = id >> 3;                  // j in [0,128)
  int bh = xcd * 8 + (j >> 4);
  int qbk = j & 15;

  int t = threadIdx.x, lane = t & 63, wave = t >> 6;
  int l15 = lane & 15, quad = lane >> 4;

  const unsigned short* qp = q_buf + (size_t)bh * S * HD;
  const unsigned short* kp = k_buf + (size_t)bh * S * HD;
  const unsigned short* vp = v_buf + (size_t)bh * HD * S;

  int q0 = qbk * 128 + wave * 32;
  bf16x8 aQ[2][2];
#pragma unroll
  for (int qf = 0; qf < 2; qf++) {
    aQ[qf][0] = *(const bf16x8*)&qp[(size_t)(q0 + qf * 16 + l15) * HD + quad * 8];
    aQ[qf][1] = *(const bf16x8*)&qp[(size_t)(q0 + qf * 16 + l15) * HD + 32 + quad * 8];
  }

  floatx4 acc_o[2][4] = {};
  float lrow[2][4] = {};

  int kr = t >> 3, kc = (t & 7) * 8;

  uint4 rK0 = *(const uint4*)&kp[(size_t)kr * HD + kc];
  uint4 rK1 = *(const uint4*)&kp[(size_t)(kr + 32) * HD + kc];
  uint4 rV0 = *(const uint4*)&vp[(size_t)kr * S + kc];
  uint4 rV1 = *(const uint4*)&vp[(size_t)(kr + 32) * S + kc];

  for (int kv = 0; kv < S; kv += 64) {
    __syncthreads();
    *(uint4*)&Ks[kr * LK + kc] = rK0;
    *(uint4*)&Ks[(kr + 32) * LK + kc] = rK1;
    *(uint4*)&Vs[kr * LV + kc] = rV0;
    *(uint4*)&Vs[(kr + 32) * LV + kc] = rV1;
    __syncthreads();
    if (kv + 64 < S) {
      rK0 = *(const uint4*)&kp[(size_t)(kv + 64 + kr) * HD + kc];
      rK1 = *(const uint4*)&kp[(size_t)(kv + 64 + kr + 32) * HD + kc];
      rV0 = *(const uint4*)&vp[(size_t)kr * S + kv + 64 + kc];
      rV1 = *(const uint4*)&vp[(size_t)(kr + 32) * S + kv + 64 + kc];
    }

    floatx4 z[2][4];
#pragma unroll
    for (int cg = 0; cg < 4; cg++) {
      bf16x8 bk0 = *(const bf16x8*)&Ks[(cg * 16 + l15) * LK + quad * 8];
      bf16x8 bk1 = *(const bf16x8*)&Ks[(cg * 16 + l15) * LK + 32 + quad * 8];
#pragma unroll
      for (int qf = 0; qf < 2; qf++) {
        floatx4 acc = {};
        acc = MFMA(aQ[qf][0], bk0, acc);
        acc = MFMA(aQ[qf][1], bk1, acc);
        z[qf][cg] = acc;
      }
    }
#pragma unroll
    for (int qf = 0; qf < 2; qf++)
#pragma unroll
      for (int cg = 0; cg < 4; cg++)
#pragma unroll
        for (int r = 0; r < 4; r++) {
          float e = __expf(z[qf][cg][r]);
          lrow[qf][r] += e;
          Ps[wave][(qf * 16 + quad * 4 + r) * LP + cg * 16 + l15] = f2bf(e);
        }
    asm volatile("s_waitcnt lgkmcnt(0)" ::: "memory");
#pragma unroll
    for (int c = 0; c < 2; c++) {
      bf16x8 aP[2];
#pragma unroll
      for (int qf = 0; qf < 2; qf++) {
        const unsigned short* pp = &Ps[wave][(qf * 16 + l15) * LP + c * 32 + quad * 8];
        ((uint2*)&aP[qf])[0] = *(const uint2*)pp;
        ((uint2*)&aP[qf])[1] = *(const uint2*)(pp + 4);
      }
#pragma unroll
      for (int n = 0; n < 4; n++) {
        bf16x8 bv = *(const bf16x8*)&Vs[(n * 16 + l15) * LV + c * 32 + quad * 8];
        acc_o[0][n] = MFMA(aP[0], bv, acc_o[0][n]);
        acc_o[1][n] = MFMA(aP[1], bv, acc_o[1][n]);
      }
    }
  }

#pragma unroll
  for (int qf = 0; qf < 2; qf++)
#pragma unroll
    for (int r = 0; r < 4; r++) {
      float s = lrow[qf][r];
#pragma unroll
      for (int off = 1; off < 16; off <<= 1) s += __shfl_xor(s, off, 16);
      lrow[qf][r] = s;
    }

  int b_ = bh >> 4, h = bh & 15;
#pragma unroll
  for (int qf = 0; qf < 2; qf++)
#pragma unroll
    for (int r = 0; r < 4; r++) {
      float inv = 1.0f / lrow[qf][r];
      int srow = q0 + qf * 16 + quad * 4 + r;
      size_t base = ((size_t)(b_ * 2048 + srow)) * 5120 + 4096 + h * 64;
#pragma unroll
      for (int n = 0; n < 4; n++)
        cat[base + n * 16 + l15] = f2bf(acc_o[qf][n][r] * inv);
    }
}

// ------------------------------------------------------------------
extern "C" void kernel_launch(void* const* d_in, const int* in_sizes, int n_in,
                              void* d_out, int out_size, void* d_ws, size_t ws_size,
                              hipStream_t stream) {
  (void)in_sizes; (void)n_in; (void)out_size; (void)ws_size;
  const float* x          = (const float*)d_in[0];
  const float* pns        = (const float*)d_in[1];
  const float* w_mlp_in   = (const float*)d_in[2];
  const float* wq         = (const float*)d_in[3];
  const float* wk         = (const float*)d_in[4];
  const float* wv         = (const float*)d_in[5];
  const float* w_mlp_out  = (const float*)d_in[6];
  const float* b_mlp_out  = (const float*)d_in[7];
  const float* w_attn_out = (const float*)d_in[8];
  const float* b_attn_out = (const float*)d_in[9];
  float* out = (float*)d_out;

  char* ws = (char*)d_ws;
  size_t off = 0;
  auto alloc = [&](size_t bytes) {
    void* p = ws + off;
    off += (bytes + 255) & ~(size_t)255;
    return p;
  };
  const size_t M = 8192;
  unsigned short* xn     = (unsigned short*)alloc(M * 1024 * 2);
  unsigned short* wcatT  = (unsigned short*)alloc((size_t)7168 * 1024 * 2);  // [mlp_in|q|k|v][N,K]
  unsigned short* wcat2T = (unsigned short*)alloc((size_t)1024 * 5120 * 2);  // [N=1024, K=5120]
  unsigned short* cat    = (unsigned short*)alloc(M * 5120 * 2);             // [h | av]
  unsigned short* qb     = (unsigned short*)alloc(M * 1024 * 2);
  unsigned short* kb     = (unsigned short*)alloc(M * 1024 * 2);
  unsigned short* vb     = (unsigned short*)alloc(M * 1024 * 2);

  transpose_all<<<dim3(12288), 256, 0, stream>>>(
      w_mlp_in, wq, wk, wv, w_mlp_out, w_attn_out, wcatT, wcat2T);

  rmsnorm_kernel<<<dim3(8192), 256, 0, stream>>>(x, pns, xn);

  // fused input GEMM: [8192,1024] x [7168,1024]^T; 256x256 tiles,
  // grid 32x28 = 896 blocks; msplit=2 nsplit=4 (tm=16,tn=7)
  gemm256_bt<6, 8><<<dim3(896), 512, 0, stream>>>(
      xn, wcatT, 1024, cat, nullptr, nullptr, nullptr, 2, 16, 7, qb, kb, vb);

  flash_attn<<<dim3(16, 64), 256, 0, stream>>>(qb, kb, vb, cat);

  // fused output GEMM: [8192,5120] x [1024,5120]^T; 128x256 tiles,
  // grid 64x4 = 256 blocks (exactly one full round); msplit=8 tm=8 tn=4
  gemm256_bt<7, 4><<<dim3(256), 512, 0, stream>>>(
      cat, wcat2T, 5120, out, b_mlp_out, b_attn_out, x, 8, 8, 4, nullptr, nullptr, nullptr);
}

// Round 3
// 549.698 us; speedup vs baseline: 1.0935x; 1.0225x over previous
//
#include <hip/hip_runtime.h>
#include <cstdint>
#include <cstddef>

typedef float floatx4 __attribute__((ext_vector_type(4)));
typedef short bf16x8 __attribute__((ext_vector_type(8)));

#define MFMA(a, b, c) __builtin_amdgcn_mfma_f32_16x16x32_bf16((a), (b), (c), 0, 0, 0)

__device__ __forceinline__ unsigned short f2bf(float f) {
  union { float f; unsigned int u; } v; v.f = f;
  unsigned int u = v.u;
  unsigned int r = (u + 0x7FFFu + ((u >> 16) & 1u)) >> 16;
  return (unsigned short)r;
}

__device__ __forceinline__ void gload_lds16(const unsigned short* g, unsigned short* s) {
  __builtin_amdgcn_global_load_lds(
      (const __attribute__((address_space(1))) unsigned int*)g,
      (__attribute__((address_space(3))) unsigned int*)s, 16, 0, 0);
}

// ------------------------------------------------------------------
// Fused prep: 6 weight transposes (ids 0..12287) + RMSNorm rows
// (ids 12288..20479).  Transpose: src [R,C] fp32 -> dst [C,R] bf16.
// RMSNorm: x [8192,1024] fp32 -> xn bf16, one block per row.
// Independent ops fused to co-schedule two BW-bound kernels.
// ------------------------------------------------------------------
__global__ __launch_bounds__(256) void prep_all(
    const float* __restrict__ w_mlp_in, const float* __restrict__ wq,
    const float* __restrict__ wk, const float* __restrict__ wv,
    const float* __restrict__ w_mlp_out, const float* __restrict__ w_attn_out,
    const float* __restrict__ x, const float* __restrict__ pns,
    unsigned short* __restrict__ wcatT, unsigned short* __restrict__ wcat2T,
    unsigned short* __restrict__ xn) {
  __shared__ float tile[32][33];
  __shared__ float ws4[4];
  int id = blockIdx.x;
  if (id >= 12288) {
    // ---- RMSNorm row
    int row = id - 12288;
    const float4 v = ((const float4*)(x + (size_t)row * 1024))[threadIdx.x];
    float ss = v.x * v.x + v.y * v.y + v.z * v.z + v.w * v.w;
#pragma unroll
    for (int off = 1; off < 64; off <<= 1) ss += __shfl_xor(ss, off, 64);
    if ((threadIdx.x & 63) == 0) ws4[threadIdx.x >> 6] = ss;
    __syncthreads();
    float tot = ws4[0] + ws4[1] + ws4[2] + ws4[3];
    float rs = rsqrtf(tot * (1.0f / 1024.0f) + 1e-6f);
    const float4 sc = ((const float4*)pns)[threadIdx.x];
    uint2 o;
    o.x = (unsigned)f2bf(v.x * rs * sc.x) | ((unsigned)f2bf(v.y * rs * sc.y) << 16);
    o.y = (unsigned)f2bf(v.z * rs * sc.z) | ((unsigned)f2bf(v.w * rs * sc.w) << 16);
    ((uint2*)(xn + (size_t)row * 1024))[threadIdx.x] = o;
    return;
  }
  // ---- transpose tile
  const float* src; unsigned short* dst; int C, ldd, bx, by, q;
  if (id < 4096)       { src = w_mlp_in;   dst = wcatT;                        C = 4096; ldd = 1024; q = id;         bx = q & 127; by = q >> 7; }
  else if (id < 5120)  { src = wq;         dst = wcatT + (size_t)4096 * 1024;  C = 1024; ldd = 1024; q = id - 4096;  bx = q & 31;  by = q >> 5; }
  else if (id < 6144)  { src = wk;         dst = wcatT + (size_t)5120 * 1024;  C = 1024; ldd = 1024; q = id - 5120;  bx = q & 31;  by = q >> 5; }
  else if (id < 7168)  { src = wv;         dst = wcatT + (size_t)6144 * 1024;  C = 1024; ldd = 1024; q = id - 6144;  bx = q & 31;  by = q >> 5; }
  else if (id < 11264) { src = w_mlp_out;  dst = wcat2T;                       C = 1024; ldd = 5120; q = id - 7168;  bx = q & 31;  by = q >> 5; }
  else                 { src = w_attn_out; dst = wcat2T + 4096;                C = 1024; ldd = 5120; q = id - 11264; bx = q & 31;  by = q >> 5; }
  int tx = threadIdx.x & 31, ty = threadIdx.x >> 5;
#pragma unroll
  for (int i = 0; i < 4; i++) {
    int r = ty + i * 8;
    tile[r][tx] = src[(size_t)(by * 32 + r) * C + bx * 32 + tx];
  }
  __syncthreads();
#pragma unroll
  for (int i = 0; i < 4; i++) {
    int r = ty + i * 8;
    dst[(size_t)(bx * 32 + r) * ldd + by * 32 + tx] = f2bf(tile[tx][r]);
  }
}

// ------------------------------------------------------------------
// GEMM: C[M,N] = A[M,K] * BT[N,K]^T (both bf16, K-major).  128x128
// tile, BK=64 as 2 x 32-k sub-buffers, 4 waves x 64x64 (R4 structure).
// PROVEN at 200 us (MODE6) / 26% MfmaUtil / 2-3 blocks per CU; the
// 256x256 1-block/CU rewrites (R1/R2) both regressed to 224 us at
// 22% regardless of schedule -- inter-block overlap is what pays here.
//
// HYBRID SWIZZLE (coalesced staging + conflict-free frag reads):
// global_load_lds forces LDS dest = base + lane*16B; the free knob is
// the lane->global map.  Lane L fetches (row = L>>2,
// granule = (L&3) ^ ((L>>3)&3)): each aligned 4-lane group covers one
// contiguous 64B global line -> coalesced.  Inverse map on the frag
// read side -> ZERO ds_read_b128 bank conflicts (measured 0).
//
// XCD swizzle: id%8 -> (M-region, N-region).
// MODE 6 (fused input): col<4096 gelu->cat[row*5120+col];
//   else q*0.125 / k scatter [B,H,S,HD], v -> [B,H,HD,S]
// MODE 7 (fused output): out[row*1024+col]=v+b1[col]+b2[col]+resid
// ------------------------------------------------------------------
template <int MODE>
__global__ __launch_bounds__(256, 2) void gemm_bt(
    const unsigned short* __restrict__ A, const unsigned short* __restrict__ BT,
    int K, void* __restrict__ outp,
    const float* __restrict__ bias1, const float* __restrict__ bias2,
    const float* __restrict__ resid,
    int msplit, int tm, int tn,
    unsigned short* __restrict__ q_out, unsigned short* __restrict__ k_out,
    unsigned short* __restrict__ v_out) {
  __shared__ unsigned short As[2][128 * 32];
  __shared__ unsigned short Bs[2][128 * 32];

  int id = blockIdx.x + gridDim.x * blockIdx.y;
  int xcd = id & 7, j = id >> 3;
  int mh = xcd % msplit, nq = xcd / msplit;
  int by = mh * tm + j / tn;
  int bx = nq * tn + j % tn;
  int m0 = by * 128, n0 = bx * 128;

  int t = threadIdx.x, lane = t & 63, wave = t >> 6;
  int l15 = lane & 15, quad = lane >> 4;
  int wm = (wave & 1) * 64, wn = (wave >> 1) * 64;

  floatx4 acc[4][4] = {};

  // staging: lane L -> global (row L>>2, granule (L&3)^((L>>3)&3))
  int lr = lane >> 2;                        // row 0..15 within chunk
  int lg = (lane & 3) ^ ((lane >> 3) & 3);   // 16B granule within row
  int ch0 = wave * 2, ch1 = wave * 2 + 1;
  const unsigned short* gA0 = A + (size_t)(m0 + ch0 * 16 + lr) * K + lg * 8;
  const unsigned short* gA1 = A + (size_t)(m0 + ch1 * 16 + lr) * K + lg * 8;
  const unsigned short* gB0 = BT + (size_t)(n0 + ch0 * 16 + lr) * K + lg * 8;
  const unsigned short* gB1 = BT + (size_t)(n0 + ch1 * 16 + lr) * K + lg * 8;
  unsigned short* sA0[2] = {&As[0][ch0 * 512 + lane * 8], &As[1][ch0 * 512 + lane * 8]};
  unsigned short* sA1[2] = {&As[0][ch1 * 512 + lane * 8], &As[1][ch1 * 512 + lane * 8]};
  unsigned short* sB0[2] = {&Bs[0][ch0 * 512 + lane * 8], &Bs[1][ch0 * 512 + lane * 8]};
  unsigned short* sB1[2] = {&Bs[0][ch1 * 512 + lane * 8], &Bs[1][ch1 * 512 + lane * 8]};

  // frag read: inverse map, conflict-free (see header comment)
  int fo = (4 * l15 + (quad ^ ((l15 >> 1) & 3))) * 8;
  int ca = (wm >> 4);  // chunk base of this wave's A rows
  int cb = (wn >> 4);

  for (int kt = 0; kt < K; kt += 64) {
    __syncthreads();
#pragma unroll
    for (int kk = 0; kk < 2; kk++) {
      int kg = kt + kk * 32;
      gload_lds16(gA0 + kg, sA0[kk]);
      gload_lds16(gA1 + kg, sA1[kk]);
      gload_lds16(gB0 + kg, sB0[kk]);
      gload_lds16(gB1 + kg, sB1[kk]);
    }
    __syncthreads();
#pragma unroll
    for (int kk = 0; kk < 2; kk++) {
      bf16x8 a[4], b[4];
#pragma unroll
      for (int im = 0; im < 4; im++)
        a[im] = *(const bf16x8*)&As[kk][(ca + im) * 512 + fo];
#pragma unroll
      for (int in_ = 0; in_ < 4; in_++)
        b[in_] = *(const bf16x8*)&Bs[kk][(cb + in_) * 512 + fo];
#pragma unroll
      for (int im = 0; im < 4; im++)
#pragma unroll
        for (int in_ = 0; in_ < 4; in_++)
          acc[im][in_] = MFMA(a[im], b[in_], acc[im][in_]);
    }
  }

#pragma unroll
  for (int im = 0; im < 4; im++) {
#pragma unroll
    for (int in_ = 0; in_ < 4; in_++) {
#pragma unroll
      for (int r = 0; r < 4; r++) {
        int row = m0 + wm + im * 16 + quad * 4 + r;
        int col = n0 + wn + in_ * 16 + l15;
        float v = acc[im][in_][r];
        if constexpr (MODE == 6) {
          if (n0 < 4096) {
            float z = 0.7978845608028654f * (v + 0.044715f * v * v * v);
            float e = __expf(2.0f * z);
            float th = 1.0f - 2.0f / (e + 1.0f);
            ((unsigned short*)outp)[(size_t)row * 5120 + col] = f2bf(0.5f * v * (1.0f + th));
          } else {
            int seg = (n0 - 4096) >> 10;          // 0=q 1=k 2=v (tile-uniform)
            int cs = col - 4096 - (seg << 10);
            int b_ = row >> 11, s = row & 2047, h = cs >> 6, hd = cs & 63;
            if (seg == 0)
              q_out[(((size_t)(b_ * 16 + h)) * 2048 + s) * 64 + hd] = f2bf(v * 0.125f);
            else if (seg == 1)
              k_out[(((size_t)(b_ * 16 + h)) * 2048 + s) * 64 + hd] = f2bf(v);
            else
              v_out[(((size_t)(b_ * 16 + h)) * 64 + hd) * 2048 + s] = f2bf(v);
          }
        } else {
          size_t idx = (size_t)row * 1024 + col;
          ((float*)outp)[idx] = v + bias1[col] + bias2[col] + resid[idx];
        }
      }
    }
  }
}

// ------------------------------------------------------------------
// Flash attention, no-max additive variant.  q pre-scaled by 0.125.
// q,k [B,H,S,HD]; v [B,H,HD,S] bf16.  av -> cat cols 4096..5120.
// 4 waves x 32 q rows; kv tile 64.
//
// R3: double-buffered Ks/Vs + ONE barrier per kv-iter (was 2).
// Iter t: write tile t+1 regs -> buf^1 (overlaps QK^T via LDS pipe),
// QK^T on buf[cur], prefetch tile t+2 -> regs (2-deep, full iter of
// HBM latency cover), exp->Ps, lgkmcnt(0) (drains Ps AND the K/V
// writes), PV on buf[cur], barrier.
// Hazards: WAR on buf[cur] (next iter overwrites it) -- all reads of
// buf[cur] are consumed by MFMAs before the barrier; W->R visibility
// of buf^1 -- pre-PV lgkm0 + end barrier.  Ps is wave-private.
// ------------------------------------------------------------------
__global__ __launch_bounds__(256, 2) void flash_attn(
    const unsigned short* __restrict__ q_buf, const unsigned short* __restrict__ k_buf,
    const unsigned short* __restrict__ v_buf, unsigned short* __restrict__ cat) {
  constexpr int S = 2048, HD = 64;
  constexpr int LK = 72, LV = 72, LP = 68;
  __shared__ unsigned short Ks[2][64 * LK];
  __shared__ unsigned short Vs[2][64 * LV];
  __shared__ unsigned short Ps[4][32 * LP];

  int id = blockIdx.x + gridDim.x * blockIdx.y;   // grid (16, 64)
  int xcd = id & 7, j = id >> 3;                  // j in [0,128)
  int bh = xcd * 8 + (j >> 4);
  int qbk = j & 15;

  int t = threadIdx.x, lane = t & 63, wave = t >> 6;
  int l15 = lane & 15, quad = lane >> 4;

  const unsigned short* qp = q_buf + (size_t)bh * S * HD;
  const unsigned short* kp = k_buf + (size_t)bh * S * HD;
  const unsigned short* vp = v_buf + (size_t)bh * HD * S;

  int q0 = qbk * 128 + wave * 32;
  bf16x8 aQ[2][2];
#pragma unroll
  for (int qf = 0; qf < 2; qf++) {
    aQ[qf][0] = *(const bf16x8*)&qp[(size_t)(q0 + qf * 16 + l15) * HD + quad * 8];
    aQ[qf][1] = *(const bf16x8*)&qp[(size_t)(q0 + qf * 16 + l15) * HD + 32 + quad * 8];
  }

  floatx4 acc_o[2][4] = {};
  float lrow[2][4] = {};

  int kr = t >> 3, kc = (t & 7) * 8;

  // tile 0 -> regs -> buf0
  uint4 rK0 = *(const uint4*)&kp[(size_t)kr * HD + kc];
  uint4 rK1 = *(const uint4*)&kp[(size_t)(kr + 32) * HD + kc];
  uint4 rV0 = *(const uint4*)&vp[(size_t)kr * S + kc];
  uint4 rV1 = *(const uint4*)&vp[(size_t)(kr + 32) * S + kc];
  *(uint4*)&Ks[0][kr * LK + kc] = rK0;
  *(uint4*)&Ks[0][(kr + 32) * LK + kc] = rK1;
  *(uint4*)&Vs[0][kr * LV + kc] = rV0;
  *(uint4*)&Vs[0][(kr + 32) * LV + kc] = rV1;
  // prefetch tile 1 -> regs
  rK0 = *(const uint4*)&kp[(size_t)(64 + kr) * HD + kc];
  rK1 = *(const uint4*)&kp[(size_t)(64 + kr + 32) * HD + kc];
  rV0 = *(const uint4*)&vp[(size_t)kr * S + 64 + kc];
  rV1 = *(const uint4*)&vp[(size_t)(kr + 32) * S + 64 + kc];
  asm volatile("s_waitcnt lgkmcnt(0)" ::: "memory");
  __syncthreads();

  for (int kv = 0; kv < S; kv += 64) {
    int cur = (kv >> 6) & 1;
    // stage tile t+1 regs -> buf^1 (overlaps with QK^T below)
    if (kv + 64 < S) {
      *(uint4*)&Ks[cur ^ 1][kr * LK + kc] = rK0;
      *(uint4*)&Ks[cur ^ 1][(kr + 32) * LK + kc] = rK1;
      *(uint4*)&Vs[cur ^ 1][kr * LV + kc] = rV0;
      *(uint4*)&Vs[cur ^ 1][(kr + 32) * LV + kc] = rV1;
    }

    floatx4 z[2][4];
#pragma unroll
    for (int cg = 0; cg < 4; cg++) {
      bf16x8 bk0 = *(const bf16x8*)&Ks[cur][(cg * 16 + l15) * LK + quad * 8];
      bf16x8 bk1 = *(const bf16x8*)&Ks[cur][(cg * 16 + l15) * LK + 32 + quad * 8];
#pragma unroll
      for (int qf = 0; qf < 2; qf++) {
        floatx4 acc = {};
        acc = MFMA(aQ[qf][0], bk0, acc);
        acc = MFMA(aQ[qf][1], bk1, acc);
        z[qf][cg] = acc;
      }
    }
    // prefetch tile t+2 -> regs (a full iteration of latency cover)
    if (kv + 128 < S) {
      rK0 = *(const uint4*)&kp[(size_t)(kv + 128 + kr) * HD + kc];
      rK1 = *(const uint4*)&kp[(size_t)(kv + 128 + kr + 32) * HD + kc];
      rV0 = *(const uint4*)&vp[(size_t)kr * S + kv + 128 + kc];
      rV1 = *(const uint4*)&vp[(size_t)(kr + 32) * S + kv + 128 + kc];
    }
#pragma unroll
    for (int qf = 0; qf < 2; qf++)
#pragma unroll
      for (int cg = 0; cg < 4; cg++)
#pragma unroll
        for (int r = 0; r < 4; r++) {
          float e = __expf(z[qf][cg][r]);
          lrow[qf][r] += e;
          Ps[wave][(qf * 16 + quad * 4 + r) * LP + cg * 16 + l15] = f2bf(e);
        }
    asm volatile("s_waitcnt lgkmcnt(0)" ::: "memory");
#pragma unroll
    for (int c = 0; c < 2; c++) {
      bf16x8 aP[2];
#pragma unroll
      for (int qf = 0; qf < 2; qf++) {
        const unsigned short* pp = &Ps[wave][(qf * 16 + l15) * LP + c * 32 + quad * 8];
        ((uint2*)&aP[qf])[0] = *(const uint2*)pp;
        ((uint2*)&aP[qf])[1] = *(const uint2*)(pp + 4);
      }
#pragma unroll
      for (int n = 0; n < 4; n++) {
        bf16x8 bv = *(const bf16x8*)&Vs[cur][(n * 16 + l15) * LV + c * 32 + quad * 8];
        acc_o[0][n] = MFMA(aP[0], bv, acc_o[0][n]);
        acc_o[1][n] = MFMA(aP[1], bv, acc_o[1][n]);
      }
    }
    __syncthreads();
  }

#pragma unroll
  for (int qf = 0; qf < 2; qf++)
#pragma unroll
    for (int r = 0; r < 4; r++) {
      float s = lrow[qf][r];
#pragma unroll
      for (int off = 1; off < 16; off <<= 1) s += __shfl_xor(s, off, 16);
      lrow[qf][r] = s;
    }

  int b_ = bh >> 4, h = bh & 15;
#pragma unroll
  for (int qf = 0; qf < 2; qf++)
#pragma unroll
    for (int r = 0; r < 4; r++) {
      float inv = 1.0f / lrow[qf][r];
      int srow = q0 + qf * 16 + quad * 4 + r;
      size_t base = ((size_t)(b_ * 2048 + srow)) * 5120 + 4096 + h * 64;
#pragma unroll
      for (int n = 0; n < 4; n++)
        cat[base + n * 16 + l15] = f2bf(acc_o[qf][n][r] * inv);
    }
}

// ------------------------------------------------------------------
extern "C" void kernel_launch(void* const* d_in, const int* in_sizes, int n_in,
                              void* d_out, int out_size, void* d_ws, size_t ws_size,
                              hipStream_t stream) {
  (void)in_sizes; (void)n_in; (void)out_size; (void)ws_size;
  const float* x          = (const float*)d_in[0];
  const float* pns        = (const float*)d_in[1];
  const float* w_mlp_in   = (const float*)d_in[2];
  const float* wq         = (const float*)d_in[3];
  const float* wk         = (const float*)d_in[4];
  const float* wv         = (const float*)d_in[5];
  const float* w_mlp_out  = (const float*)d_in[6];
  const float* b_mlp_out  = (const float*)d_in[7];
  const float* w_attn_out = (const float*)d_in[8];
  const float* b_attn_out = (const float*)d_in[9];
  float* out = (float*)d_out;

  char* ws = (char*)d_ws;
  size_t off = 0;
  auto alloc = [&](size_t bytes) {
    void* p = ws + off;
    off += (bytes + 255) & ~(size_t)255;
    return p;
  };
  const size_t M = 8192;
  unsigned short* xn     = (unsigned short*)alloc(M * 1024 * 2);
  unsigned short* wcatT  = (unsigned short*)alloc((size_t)7168 * 1024 * 2);  // [mlp_in|q|k|v][N,K]
  unsigned short* wcat2T = (unsigned short*)alloc((size_t)1024 * 5120 * 2);  // [N=1024, K=5120]
  unsigned short* cat    = (unsigned short*)alloc(M * 5120 * 2);             // [h | av]
  unsigned short* qb     = (unsigned short*)alloc(M * 1024 * 2);
  unsigned short* kb     = (unsigned short*)alloc(M * 1024 * 2);
  unsigned short* vb     = (unsigned short*)alloc(M * 1024 * 2);

  // fused transposes + rmsnorm (independent; both feed gemm6)
  prep_all<<<dim3(20480), 256, 0, stream>>>(
      w_mlp_in, wq, wk, wv, w_mlp_out, w_attn_out, x, pns, wcatT, wcat2T, xn);

  // fused input GEMM: [8192,1024] x [7168,1024]^T; 128x128 tiles,
  // grid 56x64 = 3584 blocks; msplit=2 nsplit=4 (tn=14)
  gemm_bt<6><<<dim3(56, 64), 256, 0, stream>>>(
      xn, wcatT, 1024, cat, nullptr, nullptr, nullptr, 2, 32, 14, qb, kb, vb);

  flash_attn<<<dim3(16, 64), 256, 0, stream>>>(qb, kb, vb, cat);

  // fused output GEMM: [8192,5120] x [1024,5120]^T; 128x128 tiles,
  // grid 8x64 = 512 blocks; msplit=2 nsplit=4 (tn=2)
  gemm_bt<7><<<dim3(8, 64), 256, 0, stream>>>(
      cat, wcat2T, 5120, out, b_mlp_out, b_attn_out, x, 2, 32, 2, nullptr, nullptr, nullptr);
}

// Round 5
// 541.992 us; speedup vs baseline: 1.1091x; 1.0142x over previous
//
#include <hip/hip_runtime.h>
#include <cstdint>
#include <cstddef>

typedef float floatx4 __attribute__((ext_vector_type(4)));
typedef short bf16x8 __attribute__((ext_vector_type(8)));

#define MFMA(a, b, c) __builtin_amdgcn_mfma_f32_16x16x32_bf16((a), (b), (c), 0, 0, 0)

__device__ __forceinline__ unsigned short f2bf(float f) {
  union { float f; unsigned int u; } v; v.f = f;
  unsigned int u = v.u;
  unsigned int r = (u + 0x7FFFu + ((u >> 16) & 1u)) >> 16;
  return (unsigned short)r;
}

// packed RTNE f32x2 -> bf16x2 (lo in [15:0], hi in [31:16]); bit-identical
// rounding to f2bf, 1 instr instead of ~7.
__device__ __forceinline__ unsigned int f2bf2(float lo, float hi) {
  unsigned int r;
  asm("v_cvt_pk_bf16_f32 %0, %1, %2" : "=v"(r) : "v"(lo), "v"(hi));
  return r;
}

__device__ __forceinline__ void gload_lds16(const unsigned short* g, unsigned short* s) {
  __builtin_amdgcn_global_load_lds(
      (const __attribute__((address_space(1))) unsigned int*)g,
      (__attribute__((address_space(3))) unsigned int*)s, 16, 0, 0);
}

__device__ __forceinline__ float gelu_f(float v) {
  float z = 0.7978845608028654f * (v + 0.044715f * v * v * v);
  float e = __expf(2.0f * z);
  float th = 1.0f - 2.0f / (e + 1.0f);
  return 0.5f * v * (1.0f + th);
}

// ------------------------------------------------------------------
// Fused prep: 6 weight transposes (ids 0..12287) + RMSNorm rows
// (ids 12288..20479).  Transpose: src [R,C] fp32 -> dst [C,R] bf16.
// ------------------------------------------------------------------
__global__ __launch_bounds__(256) void prep_all(
    const float* __restrict__ w_mlp_in, const float* __restrict__ wq,
    const float* __restrict__ wk, const float* __restrict__ wv,
    const float* __restrict__ w_mlp_out, const float* __restrict__ w_attn_out,
    const float* __restrict__ x, const float* __restrict__ pns,
    unsigned short* __restrict__ wcatT, unsigned short* __restrict__ wcat2T,
    unsigned short* __restrict__ xn) {
  __shared__ float tile[32][33];
  __shared__ float ws4[4];
  int id = blockIdx.x;
  if (id >= 12288) {
    // ---- RMSNorm row
    int row = id - 12288;
    const float4 v = ((const float4*)(x + (size_t)row * 1024))[threadIdx.x];
    float ss = v.x * v.x + v.y * v.y + v.z * v.z + v.w * v.w;
#pragma unroll
    for (int off = 1; off < 64; off <<= 1) ss += __shfl_xor(ss, off, 64);
    if ((threadIdx.x & 63) == 0) ws4[threadIdx.x >> 6] = ss;
    __syncthreads();
    float tot = ws4[0] + ws4[1] + ws4[2] + ws4[3];
    float rs = rsqrtf(tot * (1.0f / 1024.0f) + 1e-6f);
    const float4 sc = ((const float4*)pns)[threadIdx.x];
    uint2 o;
    o.x = f2bf2(v.x * rs * sc.x, v.y * rs * sc.y);
    o.y = f2bf2(v.z * rs * sc.z, v.w * rs * sc.w);
    ((uint2*)(xn + (size_t)row * 1024))[threadIdx.x] = o;
    return;
  }
  // ---- transpose tile
  const float* src; unsigned short* dst; int C, ldd, bx, by, q;
  if (id < 4096)       { src = w_mlp_in;   dst = wcatT;                        C = 4096; ldd = 1024; q = id;         bx = q & 127; by = q >> 7; }
  else if (id < 5120)  { src = wq;         dst = wcatT + (size_t)4096 * 1024;  C = 1024; ldd = 1024; q = id - 4096;  bx = q & 31;  by = q >> 5; }
  else if (id < 6144)  { src = wk;         dst = wcatT + (size_t)5120 * 1024;  C = 1024; ldd = 1024; q = id - 5120;  bx = q & 31;  by = q >> 5; }
  else if (id < 7168)  { src = wv;         dst = wcatT + (size_t)6144 * 1024;  C = 1024; ldd = 1024; q = id - 6144;  bx = q & 31;  by = q >> 5; }
  else if (id < 11264) { src = w_mlp_out;  dst = wcat2T;                       C = 1024; ldd = 5120; q = id - 7168;  bx = q & 31;  by = q >> 5; }
  else                 { src = w_attn_out; dst = wcat2T + 4096;                C = 1024; ldd = 5120; q = id - 11264; bx = q & 31;  by = q >> 5; }
  int tx = threadIdx.x & 31, ty = threadIdx.x >> 5;
#pragma unroll
  for (int i = 0; i < 4; i++) {
    int r = ty + i * 8;
    tile[r][tx] = src[(size_t)(by * 32 + r) * C + bx * 32 + tx];
  }
  __syncthreads();
#pragma unroll
  for (int i = 0; i < 4; i++) {
    int r = ty + i * 8;
    dst[(size_t)(bx * 32 + r) * ldd + by * 32 + tx] = f2bf(tile[tx][r]);
  }
}

// ------------------------------------------------------------------
// GEMM: C[M,N] = A[M,K] * BT[N,K]^T (both bf16, K-major).  128x128
// tile, BK=64 as 2 x 32-k sub-buffers, 4 waves x 64x64.  Proven
// structure (200 us MODE6); R1/R2 256x256 rewrites regressed.
//
// R4: ALL epilogue global writes nontemporal -- gemm6's 117 MB of
// streaming writes were evicting the per-XCD B-panel (3.7 MB, just
// fits 4 MB L2), causing 5x A/B re-fetch (FETCH 160 MB vs 31 ideal)
// and turning staging drains into ~900-cyc HBM misses.  None of the
// writes are re-read within the producing kernel.  v-scatter packed
// to one 64-bit store (s-consecutive).  cvt_pk for bf16 pairs.
//
// HYBRID SWIZZLE (0 bank conflicts measured): staging lane L ->
// (row L>>2, granule (L&3)^((L>>3)&3)); frag read
// fo=(4*l15+(quad^((l15>>1)&3)))*8.
// ------------------------------------------------------------------
template <int MODE>
__global__ __launch_bounds__(256, 2) void gemm_bt(
    const unsigned short* __restrict__ A, const unsigned short* __restrict__ BT,
    int K, void* __restrict__ outp,
    const float* __restrict__ bias1, const float* __restrict__ bias2,
    const float* __restrict__ resid,
    int msplit, int tm, int tn,
    unsigned short* __restrict__ q_out, unsigned short* __restrict__ k_out,
    unsigned short* __restrict__ v_out) {
  __shared__ unsigned short As[2][128 * 32];
  __shared__ unsigned short Bs[2][128 * 32];

  int id = blockIdx.x + gridDim.x * blockIdx.y;
  int xcd = id & 7, j = id >> 3;
  int mh = xcd % msplit, nq = xcd / msplit;
  int by = mh * tm + j / tn;
  int bx = nq * tn + j % tn;
  int m0 = by * 128, n0 = bx * 128;

  int t = threadIdx.x, lane = t & 63, wave = t >> 6;
  int l15 = lane & 15, quad = lane >> 4;
  int wm = (wave & 1) * 64, wn = (wave >> 1) * 64;

  floatx4 acc[4][4] = {};

  int lr = lane >> 2;
  int lg = (lane & 3) ^ ((lane >> 3) & 3);
  int ch0 = wave * 2, ch1 = wave * 2 + 1;
  const unsigned short* gA0 = A + (size_t)(m0 + ch0 * 16 + lr) * K + lg * 8;
  const unsigned short* gA1 = A + (size_t)(m0 + ch1 * 16 + lr) * K + lg * 8;
  const unsigned short* gB0 = BT + (size_t)(n0 + ch0 * 16 + lr) * K + lg * 8;
  const unsigned short* gB1 = BT + (size_t)(n0 + ch1 * 16 + lr) * K + lg * 8;
  unsigned short* sA0[2] = {&As[0][ch0 * 512 + lane * 8], &As[1][ch0 * 512 + lane * 8]};
  unsigned short* sA1[2] = {&As[0][ch1 * 512 + lane * 8], &As[1][ch1 * 512 + lane * 8]};
  unsigned short* sB0[2] = {&Bs[0][ch0 * 512 + lane * 8], &Bs[1][ch0 * 512 + lane * 8]};
  unsigned short* sB1[2] = {&Bs[0][ch1 * 512 + lane * 8], &Bs[1][ch1 * 512 + lane * 8]};

  int fo = (4 * l15 + (quad ^ ((l15 >> 1) & 3))) * 8;
  int ca = (wm >> 4);
  int cb = (wn >> 4);

  for (int kt = 0; kt < K; kt += 64) {
    __syncthreads();
#pragma unroll
    for (int kk = 0; kk < 2; kk++) {
      int kg = kt + kk * 32;
      gload_lds16(gA0 + kg, sA0[kk]);
      gload_lds16(gA1 + kg, sA1[kk]);
      gload_lds16(gB0 + kg, sB0[kk]);
      gload_lds16(gB1 + kg, sB1[kk]);
    }
    __syncthreads();
#pragma unroll
    for (int kk = 0; kk < 2; kk++) {
      bf16x8 a[4], b[4];
#pragma unroll
      for (int im = 0; im < 4; im++)
        a[im] = *(const bf16x8*)&As[kk][(ca + im) * 512 + fo];
#pragma unroll
      for (int in_ = 0; in_ < 4; in_++)
        b[in_] = *(const bf16x8*)&Bs[kk][(cb + in_) * 512 + fo];
#pragma unroll
      for (int im = 0; im < 4; im++)
#pragma unroll
        for (int in_ = 0; in_ < 4; in_++)
          acc[im][in_] = MFMA(a[im], b[in_], acc[im][in_]);
    }
  }

#pragma unroll
  for (int im = 0; im < 4; im++) {
#pragma unroll
    for (int in_ = 0; in_ < 4; in_++) {
      int row0 = m0 + wm + im * 16 + quad * 4;
      int col = n0 + wn + in_ * 16 + l15;
      if constexpr (MODE == 6) {
        if (n0 < 4096) {
#pragma unroll
          for (int r = 0; r < 4; r += 2) {
            unsigned u = f2bf2(gelu_f(acc[im][in_][r]), gelu_f(acc[im][in_][r + 1]));
            __builtin_nontemporal_store((unsigned short)u,
                &((unsigned short*)outp)[(size_t)(row0 + r) * 5120 + col]);
            __builtin_nontemporal_store((unsigned short)(u >> 16),
                &((unsigned short*)outp)[(size_t)(row0 + r + 1) * 5120 + col]);
          }
        } else {
          int seg = (n0 - 4096) >> 10;          // 0=q 1=k 2=v (tile-uniform)
          int cs = col - 4096 - (seg << 10);
          int h = cs >> 6, hd = cs & 63;
          int b_ = row0 >> 11, s0 = row0 & 2047;
          if (seg == 2) {
            // s-consecutive: pack 4 bf16 -> one 64-bit store
            unsigned long long o =
                (unsigned long long)f2bf2(acc[im][in_][0], acc[im][in_][1]) |
                ((unsigned long long)f2bf2(acc[im][in_][2], acc[im][in_][3]) << 32);
            __builtin_nontemporal_store(o,
                (unsigned long long*)&v_out[(((size_t)(b_ * 16 + h)) * 64 + hd) * 2048 + s0]);
          } else {
            float sc = (seg == 0) ? 0.125f : 1.0f;
            unsigned short* dst = (seg == 0) ? q_out : k_out;
#pragma unroll
            for (int r = 0; r < 4; r += 2) {
              unsigned u = f2bf2(acc[im][in_][r] * sc, acc[im][in_][r + 1] * sc);
              __builtin_nontemporal_store((unsigned short)u,
                  &dst[(((size_t)(b_ * 16 + h)) * 2048 + s0 + r) * 64 + hd]);
              __builtin_nontemporal_store((unsigned short)(u >> 16),
                  &dst[(((size_t)(b_ * 16 + h)) * 2048 + s0 + r + 1) * 64 + hd]);
            }
          }
        }
      } else {
        float bsum = bias1[col] + bias2[col];
#pragma unroll
        for (int r = 0; r < 4; r++) {
          size_t idx = (size_t)(row0 + r) * 1024 + col;
          float res = __builtin_nontemporal_load(&resid[idx]);
          __builtin_nontemporal_store(acc[im][in_][r] + bsum + res, &((float*)outp)[idx]);
        }
      }
    }
  }
}

// ------------------------------------------------------------------
// Flash attention, no-max additive variant.  q pre-scaled by 0.125.
// q,k [B,H,S,HD]; v [B,H,HD,S] bf16.  av -> cat cols 4096..5120.
// 4 waves x 32 q rows; kv tile 64; double-buffered K/V, 1 barrier/iter.
//
// R4: LK/LV/LP 72/72/68 -> 68 (LDS 54272 -> 52224 B: guarantees
// 3 blocks/CU even at 2 KB alloc granularity; stride-68 b128 reads
// are conflict-free per 16-lane phase: banks 2*l15+4q+j distinct).
// launch_bounds(256,3) keeps VGPR <= 170 for 3-block residency.
// cvt_pk halves the bf16-pack cost in the softmax path (the per-iter
// serial chain QK^T -> exp/pack -> PV is the bottleneck).
// ------------------------------------------------------------------
__global__ __launch_bounds__(256, 3) void flash_attn(
    const unsigned short* __restrict__ q_buf, const unsigned short* __restrict__ k_buf,
    const unsigned short* __restrict__ v_buf, unsigned short* __restrict__ cat) {
  constexpr int S = 2048, HD = 64;
  constexpr int LK = 68, LV = 68, LP = 68;
  __shared__ unsigned short Ks[2][64 * LK];
  __shared__ unsigned short Vs[2][64 * LV];
  __shared__ unsigned short Ps[4][32 * LP];

  int id = blockIdx.x + gridDim.x * blockIdx.y;   // grid (16, 64)
  int xcd = id & 7, j = id >> 3;                  // j in [0,128)
  int bh = xcd * 8 + (j >> 4);
  int qbk = j & 15;

  int t = threadIdx.x, lane = t & 63, wave = t >> 6;
  int l15 = lane & 15, quad = lane >> 4;

  const unsigned short* qp = q_buf + (size_t)bh * S * HD;
  const unsigned short* kp = k_buf + (size_t)bh * S * HD;
  const unsigned short* vp = v_buf + (size_t)bh * HD * S;

  int q0 = qbk * 128 + wave * 32;
  bf16x8 aQ[2][2];
#pragma unroll
  for (int qf = 0; qf < 2; qf++) {
    aQ[qf][0] = *(const bf16x8*)&qp[(size_t)(q0 + qf * 16 + l15) * HD + quad * 8];
    aQ[qf][1] = *(const bf16x8*)&qp[(size_t)(q0 + qf * 16 + l15) * HD + 32 + quad * 8];
  }

  floatx4 acc_o[2][4] = {};
  float lrow[2][4] = {};

  int kr = t >> 3, kc = (t & 7) * 8;

  // tile 0 -> regs -> buf0
  uint4 rK0 = *(const uint4*)&kp[(size_t)kr * HD + kc];
  uint4 rK1 = *(const uint4*)&kp[(size_t)(kr + 32) * HD + kc];
  uint4 rV0 = *(const uint4*)&vp[(size_t)kr * S + kc];
  uint4 rV1 = *(const uint4*)&vp[(size_t)(kr + 32) * S + kc];
  *(uint4*)&Ks[0][kr * LK + kc] = rK0;
  *(uint4*)&Ks[0][(kr + 32) * LK + kc] = rK1;
  *(uint4*)&Vs[0][kr * LV + kc] = rV0;
  *(uint4*)&Vs[0][(kr + 32) * LV + kc] = rV1;
  // prefetch tile 1 -> regs
  rK0 = *(const uint4*)&kp[(size_t)(64 + kr) * HD + kc];
  rK1 = *(const uint4*)&kp[(size_t)(64 + kr + 32) * HD + kc];
  rV0 = *(const uint4*)&vp[(size_t)kr * S + 64 + kc];
  rV1 = *(const uint4*)&vp[(size_t)(kr + 32) * S + 64 + kc];
  asm volatile("s_waitcnt lgkmcnt(0)" ::: "memory");
  __syncthreads();

  for (int kv = 0; kv < S; kv += 64) {
    int cur = (kv >> 6) & 1;
    // stage tile t+1 regs -> buf^1 (overlaps with QK^T below)
    if (kv + 64 < S) {
      *(uint4*)&Ks[cur ^ 1][kr * LK + kc] = rK0;
      *(uint4*)&Ks[cur ^ 1][(kr + 32) * LK + kc] = rK1;
      *(uint4*)&Vs[cur ^ 1][kr * LV + kc] = rV0;
      *(uint4*)&Vs[cur ^ 1][(kr + 32) * LV + kc] = rV1;
    }

    floatx4 z[2][4];
#pragma unroll
    for (int cg = 0; cg < 4; cg++) {
      bf16x8 bk0 = *(const bf16x8*)&Ks[cur][(cg * 16 + l15) * LK + quad * 8];
      bf16x8 bk1 = *(const bf16x8*)&Ks[cur][(cg * 16 + l15) * LK + 32 + quad * 8];
#pragma unroll
      for (int qf = 0; qf < 2; qf++) {
        floatx4 acc = {};
        acc = MFMA(aQ[qf][0], bk0, acc);
        acc = MFMA(aQ[qf][1], bk1, acc);
        z[qf][cg] = acc;
      }
    }
    // prefetch tile t+2 -> regs
    if (kv + 128 < S) {
      rK0 = *(const uint4*)&kp[(size_t)(kv + 128 + kr) * HD + kc];
      rK1 = *(const uint4*)&kp[(size_t)(kv + 128 + kr + 32) * HD + kc];
      rV0 = *(const uint4*)&vp[(size_t)kr * S + kv + 128 + kc];
      rV1 = *(const uint4*)&vp[(size_t)(kr + 32) * S + kv + 128 + kc];
    }
#pragma unroll
    for (int qf = 0; qf < 2; qf++)
#pragma unroll
      for (int cg = 0; cg < 4; cg++) {
        float e0 = __expf(z[qf][cg][0]);
        float e1 = __expf(z[qf][cg][1]);
        float e2 = __expf(z[qf][cg][2]);
        float e3 = __expf(z[qf][cg][3]);
        lrow[qf][0] += e0; lrow[qf][1] += e1;
        lrow[qf][2] += e2; lrow[qf][3] += e3;
        unsigned p01 = f2bf2(e0, e1), p23 = f2bf2(e2, e3);
        unsigned short* base = &Ps[wave][(qf * 16 + quad * 4) * LP + cg * 16 + l15];
        base[0 * LP] = (unsigned short)p01;
        base[1 * LP] = (unsigned short)(p01 >> 16);
        base[2 * LP] = (unsigned short)p23;
        base[3 * LP] = (unsigned short)(p23 >> 16);
      }
    asm volatile("s_waitcnt lgkmcnt(0)" ::: "memory");
#pragma unroll
    for (int c = 0; c < 2; c++) {
      bf16x8 aP[2];
#pragma unroll
      for (int qf = 0; qf < 2; qf++) {
        const unsigned short* pp = &Ps[wave][(qf * 16 + l15) * LP + c * 32 + quad * 8];
        ((uint2*)&aP[qf])[0] = *(const uint2*)pp;
        ((uint2*)&aP[qf])[1] = *(const uint2*)(pp + 4);
      }
#pragma unroll
      for (int n = 0; n < 4; n++) {
        bf16x8 bv = *(const bf16x8*)&Vs[cur][(n * 16 + l15) * LV + c * 32 + quad * 8];
        acc_o[0][n] = MFMA(aP[0], bv, acc_o[0][n]);
        acc_o[1][n] = MFMA(aP[1], bv, acc_o[1][n]);
      }
    }
    __syncthreads();
  }

#pragma unroll
  for (int qf = 0; qf < 2; qf++)
#pragma unroll
    for (int r = 0; r < 4; r++) {
      float s = lrow[qf][r];
#pragma unroll
      for (int off = 1; off < 16; off <<= 1) s += __shfl_xor(s, off, 16);
      lrow[qf][r] = s;
    }

  int b_ = bh >> 4, h = bh & 15;
#pragma unroll
  for (int qf = 0; qf < 2; qf++)
#pragma unroll
    for (int r = 0; r < 4; r++) {
      float inv = 1.0f / lrow[qf][r];
      int srow = q0 + qf * 16 + quad * 4 + r;
      size_t base = ((size_t)(b_ * 2048 + srow)) * 5120 + 4096 + h * 64;
      unsigned u01 = f2bf2(acc_o[qf][0][r] * inv, acc_o[qf][1][r] * inv);
      unsigned u23 = f2bf2(acc_o[qf][2][r] * inv, acc_o[qf][3][r] * inv);
      __builtin_nontemporal_store((unsigned short)u01,        &cat[base + 0 * 16 + l15]);
      __builtin_nontemporal_store((unsigned short)(u01 >> 16), &cat[base + 1 * 16 + l15]);
      __builtin_nontemporal_store((unsigned short)u23,        &cat[base + 2 * 16 + l15]);
      __builtin_nontemporal_store((unsigned short)(u23 >> 16), &cat[base + 3 * 16 + l15]);
    }
}

// ------------------------------------------------------------------
extern "C" void kernel_launch(void* const* d_in, const int* in_sizes, int n_in,
                              void* d_out, int out_size, void* d_ws, size_t ws_size,
                              hipStream_t stream) {
  (void)in_sizes; (void)n_in; (void)out_size; (void)ws_size;
  const float* x          = (const float*)d_in[0];
  const float* pns        = (const float*)d_in[1];
  const float* w_mlp_in   = (const float*)d_in[2];
  const float* wq         = (const float*)d_in[3];
  const float* wk         = (const float*)d_in[4];
  const float* wv         = (const float*)d_in[5];
  const float* w_mlp_out  = (const float*)d_in[6];
  const float* b_mlp_out  = (const float*)d_in[7];
  const float* w_attn_out = (const float*)d_in[8];
  const float* b_attn_out = (const float*)d_in[9];
  float* out = (float*)d_out;

  char* ws = (char*)d_ws;
  size_t off = 0;
  auto alloc = [&](size_t bytes) {
    void* p = ws + off;
    off += (bytes + 255) & ~(size_t)255;
    return p;
  };
  const size_t M = 8192;
  unsigned short* xn     = (unsigned short*)alloc(M * 1024 * 2);
  unsigned short* wcatT  = (unsigned short*)alloc((size_t)7168 * 1024 * 2);  // [mlp_in|q|k|v][N,K]
  unsigned short* wcat2T = (unsigned short*)alloc((size_t)1024 * 5120 * 2);  // [N=1024, K=5120]
  unsigned short* cat    = (unsigned short*)alloc(M * 5120 * 2);             // [h | av]
  unsigned short* qb     = (unsigned short*)alloc(M * 1024 * 2);
  unsigned short* kb     = (unsigned short*)alloc(M * 1024 * 2);
  unsigned short* vb     = (unsigned short*)alloc(M * 1024 * 2);

  // fused transposes + rmsnorm (independent; both feed gemm6)
  prep_all<<<dim3(20480), 256, 0, stream>>>(
      w_mlp_in, wq, wk, wv, w_mlp_out, w_attn_out, x, pns, wcatT, wcat2T, xn);

  // fused input GEMM: [8192,1024] x [7168,1024]^T; 128x128 tiles,
  // grid 56x64 = 3584 blocks; msplit=2 nsplit=4 (tn=14)
  gemm_bt<6><<<dim3(56, 64), 256, 0, stream>>>(
      xn, wcatT, 1024, cat, nullptr, nullptr, nullptr, 2, 32, 14, qb, kb, vb);

  flash_attn<<<dim3(16, 64), 256, 0, stream>>>(qb, kb, vb, cat);

  // fused output GEMM: [8192,5120] x [1024,5120]^T; 128x128 tiles,
  // grid 8x64 = 512 blocks; msplit=2 nsplit=4 (tn=2)
  gemm_bt<7><<<dim3(8, 64), 256, 0, stream>>>(
      cat, wcat2T, 5120, out, b_mlp_out, b_attn_out, x, 2, 32, 2, nullptr, nullptr, nullptr);
}